// Round 14
// baseline (83.703 us; speedup 1.0000x reference)
//
#include <hip/hip_runtime.h>

#define BS 4096
#define LL 512
#define NW 16                 // waves per block = chunks per batch-group
#define SS 32                 // own steps per chunk
#define WU 8                  // warm-up steps for chunks c>=1 (contraction ~0.1^8)
#define NB 16                 // batches per block (= MFMA columns)
#define START_TAG 1
#define END_TAG 2
#define BIASF 4.5f            // per-applied-step 2^-BIASF (restored exactly in log2)
#define L2E 1.44269504f
#define LN2 0.69314718055994531f

typedef float f32x4 __attribute__((ext_vector_type(4)));
typedef short s16x4 __attribute__((ext_vector_type(4)));
union BF4 { unsigned u[2]; s16x4 s; };

__device__ __forceinline__ unsigned cvt_pk_bf16(float lo, float hi) {
    unsigned r;
    asm("v_cvt_pk_bf16_f32 %0, %1, %2" : "=v"(r) : "v"(lo), "v"(hi));
    return r;
}
__device__ __forceinline__ float blo(unsigned u) { return __uint_as_float(u << 16); }
__device__ __forceinline__ float bhi(unsigned u) { return __uint_as_float(u & 0xFFFF0000u); }

// Vec-mode CRF with warm-up chunk chaining (fwd-only; validated r13 identity).
// Block = 16 batches, 16 waves = 16 chunks of 32 steps. MFMA columns = batches.
// Pass 1: wave c runs steps [32c-WU, 32(c+1)) from ones -> y_c (alpha direction).
// Pass 2: wave c>=1 re-runs its own 32 steps from y_{c-1} -> r_c = P_c y_{c-1}.
// Chain:  dlog2 = log2(sum r_c) - log2(sum y_c) + G_c + F_{c-1} - F_c.
__global__ __launch_bounds__(1024, 1) void crf_wu2(
    const float* __restrict__ em, const int* __restrict__ tg,
    const float* __restrict__ mk, const float* __restrict__ tr,
    float* __restrict__ out)
{
    __shared__ float sY[NW][NB][16];   // pass-1 results [chunk][batch][row]
    __shared__ float sR[NW][NB][16];   // pass-2 results (c>=1)
    __shared__ float sF[NW][NB];       // pass-1 log2 exponents (renorm + BIASF)
    __shared__ float sG[NW][NB];       // pass-2 log2 exponents
    __shared__ float sSc[NB], sCnt[NB], sRes[NB];

    const int tid  = threadIdx.x;
    const int wv   = tid >> 6;
    const int lane = tid & 63;
    const int j    = lane & 15;        // MFMA column = batch-in-block
    const int q    = lane >> 4;        // row-block (rows 4q..4q+3)
    const long gb0 = (long)blockIdx.x * NB;
    const long b   = gb0 + j;          // this lane's batch

    // tags dtype detect (validated): 16 u64 words all <16 => int64 layout
    int is64 = 1;
    {
        const unsigned long long* t64 = (const unsigned long long*)tg;
#pragma unroll
        for (int i = 0; i < 16; ++i) is64 &= (t64[i] < 16ull) ? 1 : 0;
    }
    const int esz = is64 ? 2 : 1;

    // static A = E^T: lane (j,q) holds A[j][4q+i] = exp(tr[4q+i][j])  (validated)
    BF4 Af;
    {
        float Ef[4];
#pragma unroll
        for (int i = 0; i < 4; ++i)
            Ef[i] = exp2f(tr[(q * 4 + i) * 16 + j] * L2E);   // exp(-1000) -> 0
        Af.u[0] = cvt_pk_bf16(Ef[0], Ef[1]);
        Af.u[1] = cvt_pk_bf16(Ef[2], Ef[3]);
    }

    // ---- chain runner: steps [t0, t0+ns) of batch b (r4/r13-validated math) ----
    auto chain = [&](int t0, int ns, unsigned& p01, unsigned& p23,
                     float& e2f, float& cnt) {
        const float* pe = em + (((long)b * LL + t0) << 4) + (q << 2);
        const float* pm = mk + (long)b * LL + t0;
        f32x4 evc[4], evn[4], mc, mn;
#pragma unroll
        for (int s = 0; s < 4; ++s) evc[s] = *(const f32x4*)(pe + s * 16);
        mc = *(const f32x4*)(pm);
        const int ng = ns >> 2;
        for (int gi = 0; gi < ng; ++gi) {
            const int g = gi << 2;
            if (gi + 1 < ng) {
#pragma unroll
                for (int s = 0; s < 4; ++s)
                    evn[s] = *(const f32x4*)(pe + ((g + 4 + s) << 4));
                mn = *(const f32x4*)(pm + g + 4);
            }
#pragma unroll
            for (int s = 0; s < 4; ++s) {
                const float e0 = exp2f(fmaf(evc[s].x, L2E, -BIASF));
                const float e1 = exp2f(fmaf(evc[s].y, L2E, -BIASF));
                const float e2 = exp2f(fmaf(evc[s].z, L2E, -BIASF));
                const float e3 = exp2f(fmaf(evc[s].w, L2E, -BIASF));
                BF4 Bf; Bf.u[0] = p01; Bf.u[1] = p23;
                f32x4 z = {0.f, 0.f, 0.f, 0.f};
                f32x4 d = __builtin_amdgcn_mfma_f32_16x16x16bf16_1k(Af.s, Bf.s, z, 0, 0, 0);
                const unsigned n01 = cvt_pk_bf16(d[0] * e0, d[1] * e1);
                const unsigned n23 = cvt_pk_bf16(d[2] * e2, d[3] * e3);
                const bool up = mc[s] > 0.f;       // per-column mask select
                p01 = up ? n01 : p01;
                p23 = up ? n23 : p23;
                cnt += mc[s];
            }
            // exact pow2 renorm every 16 steps and at the final group
            if (((gi & 3) == 3) || (gi == ng - 1)) {
                const float v0 = blo(p01), v1 = bhi(p01), v2 = blo(p23), v3 = bhi(p23);
                float mm = fmaxf(fmaxf(v0, v1), fmaxf(v2, v3));
                mm = fmaxf(mm, __shfl_xor(mm, 16));
                mm = fmaxf(mm, __shfl_xor(mm, 32));
                if (mm > 0.f) {
                    const int ex = (int)((__float_as_uint(mm) >> 23) & 0xFFu) - 127;
                    const float sre = __uint_as_float((unsigned)(127 - ex) << 23);
                    e2f += (float)ex;
                    p01 = cvt_pk_bf16(v0 * sre, v1 * sre);
                    p23 = cvt_pk_bf16(v2 * sre, v3 * sre);
                }
            }
            if (gi + 1 < ng) {
#pragma unroll
                for (int s = 0; s < 4; ++s) evc[s] = evn[s];
                mc = mn;
            }
        }
    };

    // ---- pass 1: warmed chunk chains from ones ----
    {
        unsigned p01 = 0x3F803F80u, p23 = 0x3F803F80u;
        float e2f = 0.f, cntc = 0.f;
        const int warm = (wv == 0) ? 0 : WU;
        chain(wv * SS - warm, SS + warm, p01, p23, e2f, cntc);
        sY[wv][j][q * 4 + 0] = blo(p01);
        sY[wv][j][q * 4 + 1] = bhi(p01);
        sY[wv][j][q * 4 + 2] = blo(p23);
        sY[wv][j][q * 4 + 3] = bhi(p23);
        if (lane < 16) sF[wv][j] = e2f + BIASF * cntc;
    }

    // ---- path score + mask count: wave wv handles batch wv ----
    {
        const long base = (gb0 + wv) * (long)LL;
        float part = 0.f, cpart = 0.f;
#pragma unroll
        for (int k = 0; k < 8; ++k) {
            const int t = (k << 6) + lane;
            const int tcur = tg[(base + t) * esz];
            const int tpv  = (t == 0) ? START_TAG : (int)tg[(base + t - 1) * esz];
            const float m  = mk[base + t];
            const float scm = (t == 0) ? 1.f : m;
            part = fmaf(em[((base + t) << 4) + tcur] + tr[tpv * 16 + tcur], scm, part);
            cpart += m;
        }
#pragma unroll
        for (int o = 1; o <= 32; o <<= 1) {
            part  += __shfl_xor(part, o);
            cpart += __shfl_xor(cpart, o);
        }
        if (lane == 0) { sSc[wv] = part; sCnt[wv] = cpart; }
    }
    __syncthreads();

    // ---- pass 2: re-run own 32 steps from y_{c-1} (waves 1..15) ----
    if (wv >= 1) {
        const f32x4 y4 = *(const f32x4*)(&sY[wv - 1][j][q * 4]);
        unsigned r01 = cvt_pk_bf16(y4.x, y4.y);
        unsigned r23 = cvt_pk_bf16(y4.z, y4.w);
        float g2f = 0.f, cnt2 = 0.f;
        chain(wv * SS, SS, r01, r23, g2f, cnt2);
        sR[wv][j][q * 4 + 0] = blo(r01);
        sR[wv][j][q * 4 + 1] = bhi(r01);
        sR[wv][j][q * 4 + 2] = blo(r23);
        sR[wv][j][q * 4 + 3] = bhi(r23);
        if (lane < 16) sG[wv][j] = g2f + BIASF * cnt2;
    }
    __syncthreads();

    // ---- combine: 256 threads = 16 batches x 16 components ----
    if (tid < 256) {
        const int bi = tid >> 4, row = tid & 15;
        float x = sY[NW - 1][bi][row] * exp2f(tr[row * 16 + END_TAG] * L2E);
#pragma unroll
        for (int o = 1; o <= 8; o <<= 1) x += __shfl_xor(x, o, 16);
        float l2 = log2f(fmaxf(x, 1e-35f)) + sF[NW - 1][bi];
#pragma unroll
        for (int c2 = 1; c2 < NW; ++c2) {
            float num = sR[c2][bi][row];
            float den = sY[c2][bi][row];
#pragma unroll
            for (int o = 1; o <= 8; o <<= 1) {
                num += __shfl_xor(num, o, 16);
                den += __shfl_xor(den, o, 16);
            }
            l2 += log2f(fmaxf(num, 1e-35f)) - log2f(fmaxf(den, 1e-35f))
                + sG[c2][bi] + sF[c2 - 1][bi] - sF[c2][bi];
        }
        if (row == 0) {
            const float dp = LN2 * l2;
            const int li = (int)sCnt[bi] - 1;
            const int lt = tg[((gb0 + bi) * (long)LL + li) * esz];
            sRes[bi] = dp - (sSc[bi] + tr[lt * 16 + END_TAG]);
        }
    }
    __syncthreads();
    if (tid == 0) {
        float s = 0.f;
#pragma unroll
        for (int i = 0; i < NB; ++i) s += sRes[i];
        atomicAdd(out, s);
    }
}

extern "C" void kernel_launch(void* const* d_in, const int* in_sizes, int n_in,
                              void* d_out, int out_size, void* d_ws, size_t ws_size,
                              hipStream_t stream) {
    const float* em = (const float*)d_in[0];
    const int*   tg = (const int*)d_in[1];
    const float* mk = (const float*)d_in[2];
    const float* tr = (const float*)d_in[3];
    float* out = (float*)d_out;

    hipMemsetAsync(out, 0, sizeof(float), stream);
    crf_wu2<<<BS / NB, 1024, 0, stream>>>(em, tg, mk, tr, out);
}